// Round 7
// baseline (8982.985 us; speedup 1.0000x reference)
//
#include <hip/hip_runtime.h>
#include <math.h>
#include <stdint.h>

// ---------------------------------------------------------------------------
// Speller decoder, persistent kernel, 512 blocks x 256 threads.
// R10 = R9 resubmit (prior bench died at container level, no kernel signal).
// R9: cached data-plane loads + acquire fences. R8's counters showed the
// AGENT-scope (sc0 sc1) loads bypass L1/L2: FETCH 39 MB/step for a 2 MB
// working set, at 376 GB/s = the concurrency-limited HBM-latency ceiling —
// i.e. the WHOLE step time was serialized coherent-load service. Now:
// stores to shared state stay relaxed AGENT atomics (bypass to L3), but all
// data-plane LOADS are plain cached loads; coherence is restored by
// __builtin_amdgcn_fence(ACQUIRE,"agent") (= buffer_inv, invalidates
// vL1+XCD-L2) at every consume edge: inside gsync after the flag trips, and
// after the W2/W4 intra-phase arrival spins. Per phase the broadcast data
// is read once from L3 per XCD, then L2/L1 hits.
// R8: phase-1 A-part (ctx|h) pipelined into the W3 window. R7/R6: LF
// register-resident (128 VGPR/thread; phase-2 attention has zero LF memory
// traffic; keep/send reduce-scatter). R5: parallel per-batch phase-4 merge.
// R3: monotonic counter barriers.
// ---------------------------------------------------------------------------

#define NB 512
#define NT 256

constexpr int Tv = 1024, Vv = 5000, STEPS = 64;

// ---- u32 counter region (all monotonic, zeroed by init kernel) ----
constexpr int MCNT = 0;               // master barrier counter
constexpr int GEN  = 16;              // barrier generation
constexpr int GCNT = 64;              // 32 group counters, stride 16
constexpr int GFLG = 1024;            // 32 group release flags, stride 32
constexpr int ACNT = 2048;            // 32 attn-merge counters, stride 16
constexpr int LCNT = 2560;            // single logits-arrival counter
constexpr int WSU  = 4096;

// ---- float region offsets (wsf = (float*)ws + WSU) ----
constexpr int XH   = 0;                    // [32][1024] = emb(512) | ctx(512)
constexpr int HB   = XH + 32*1024;         // [2][32][512] h double-buffer
constexpr int HID  = HB + 2*32*512;        // [32][512]
constexpr int PART = HID + 32*512;         // [32][4][16][130] attn partials
constexpr int E3   = PART + 32*4*16*130;   // [32][1024] head-3 energies
constexpr int PM   = E3 + 32*1024;         // [32][256] chunk max
constexpr int PSUM = PM + 32*256;          // [32][256] chunk sumexp
constexpr int PIDX = PSUM + 32*256;        // [32][256] chunk argmax (int)
constexpr int MLS  = PIDX + 32*256;        // [32][2] (max, lse)

__device__ __forceinline__ float sigm(float x) { return 1.f / (1.f + expf(-x)); }

// ---- acquire fence: buffer_inv (vL1 + XCD L2) so plain loads see L3 ----
__device__ __forceinline__ void fence_acq() {
  __builtin_amdgcn_fence(__ATOMIC_ACQUIRE, "agent");
}

// ---- data-plane LOADS: plain cached (valid only after a fence_acq edge) --
__device__ __forceinline__ float ld4(const float* p)  { return *p; }
__device__ __forceinline__ float2 ld8(const float* p) { return *(const float2*)p; }
__device__ __forceinline__ int   ld4i(const int* p)   { return *p; }

// ---- data-plane STORES: relaxed AGENT atomics (bypass L2, land in L3) ----
__device__ __forceinline__ void st4(float* p, float v) {
  __hip_atomic_store(p, v, __ATOMIC_RELAXED, __HIP_MEMORY_SCOPE_AGENT);
}
__device__ __forceinline__ void st8(float* p, float2 v) {
  union { float2 f; unsigned long long u; } c; c.f = v;
  __hip_atomic_store(reinterpret_cast<unsigned long long*>(p), c.u,
                     __ATOMIC_RELAXED, __HIP_MEMORY_SCOPE_AGENT);
}
__device__ __forceinline__ void st4i(int* p, int v) {
  __hip_atomic_store(reinterpret_cast<unsigned*>(p), (unsigned)v,
                     __ATOMIC_RELAXED, __HIP_MEMORY_SCOPE_AGENT);
}
__device__ __forceinline__ unsigned ld_rlx(unsigned* p) {
  return __hip_atomic_load(p, __ATOMIC_RELAXED, __HIP_MEMORY_SCOPE_AGENT);
}
__device__ __forceinline__ void st_rlx(unsigned* p, unsigned v) {
  __hip_atomic_store(p, v, __ATOMIC_RELAXED, __HIP_MEMORY_SCOPE_AGENT);
}
__device__ __forceinline__ unsigned add_rlx(unsigned* p, unsigned v) {
  return __hip_atomic_fetch_add(p, v, __ATOMIC_RELAXED, __HIP_MEMORY_SCOPE_AGENT);
}

// Device barrier. __syncthreads drains vmcnt (sc1 stores then in L3);
// counters are relaxed sc1 atomics; the ACQUIRE fence after the flag trips
// invalidates vL1/L2 so the next phase's plain loads refill from L3.
__device__ __forceinline__ void gsync(unsigned* wsu, int blk, int tid, unsigned& myGen) {
  __syncthreads();
  if (tid == 0) {
    const unsigned target = ++myGen;
    const int grp = blk >> 4;
    unsigned o = add_rlx(&wsu[GCNT + grp*16], 1u);
    if (o == target*16u - 1u) {
      unsigned o2 = add_rlx(&wsu[MCNT], 1u);
      if (o2 == target*32u - 1u) st_rlx(&wsu[GEN], target);
    }
    if ((blk & 15) == 0) {
      while (ld_rlx(&wsu[GEN]) != target) __builtin_amdgcn_s_sleep(8);
      st_rlx(&wsu[GFLG + grp*32], target);
    } else {
      while (ld_rlx(&wsu[GFLG + grp*32]) != target) __builtin_amdgcn_s_sleep(8);
    }
    fence_acq();
  }
  __syncthreads();
}

__global__ void speller_init(const float* __restrict__ LF, const float* __restrict__ Emb,
                             float* __restrict__ wsf, unsigned* __restrict__ wsu) {
  int b = blockIdx.x;
  for (int i = threadIdx.x; i < 512; i += NT) {
    st4(wsf + XH + b*1024 + i,       Emb[i]);                    // emb row 0
    st4(wsf + XH + b*1024 + 512 + i, LF[(size_t)b*Tv*512 + i]);  // ctx0 = LF[b,0,:]
    st4(wsf + HB + b*512 + i,        0.f);                       // h0 (buffer 0)
  }
  if (b == 0) for (int i = threadIdx.x; i < WSU; i += NT) st_rlx(wsu + i, 0u);
}

struct LdsA { float Wg[8][1536]; float gb[8]; };   // gate rows: i,i,f,f,g,g,o,o of units 2j,2j+1
struct LdsB { float Wc[20][512]; float Wp[2][1024]; float bcl[20]; float bpl[2]; };
union  LdsU { LdsA a; LdsB b; };

// A-part of the gate GEMM for one step: K in [512,1536) = ctx | h.
// acc[8][2] accumulates rows (gate,unit) x 2 batches for lane (slot,ks).
__device__ __forceinline__ void gate_accum_A(float acc[8][2], const float* __restrict__ wsf,
                                             const float (&Wg)[8][1536],
                                             int ks, int b0, int hbuf) {
#pragma unroll 2
  for (int q = 0; q < 8; ++q) {              // ctx: k in [512,1024)
    const int k4 = 512 + (q*16 + ks)*4;
    float2 xa[2], xb[2];
#pragma unroll
    for (int i = 0; i < 2; ++i) {
      const float* p = wsf + XH + (size_t)(b0+i)*1024 + k4;
      xa[i] = ld8(p); xb[i] = ld8(p + 2);
    }
#pragma unroll
    for (int r = 0; r < 8; ++r) {
      float4 wv = *(const float4*)(&Wg[r][k4]);
#pragma unroll
      for (int i = 0; i < 2; ++i)
        acc[r][i] += wv.x*xa[i].x + wv.y*xa[i].y + wv.z*xb[i].x + wv.w*xb[i].y;
    }
  }
#pragma unroll 2
  for (int q = 0; q < 8; ++q) {              // h: k in [1024,1536)
    const int k4 = (q*16 + ks)*4;
    float2 xa[2], xb[2];
#pragma unroll
    for (int i = 0; i < 2; ++i) {
      const float* p = wsf + HB + hbuf*16384 + (size_t)(b0+i)*512 + k4;
      xa[i] = ld8(p); xb[i] = ld8(p + 2);
    }
#pragma unroll
    for (int r = 0; r < 8; ++r) {
      float4 wv = *(const float4*)(&Wg[r][1024 + k4]);
#pragma unroll
      for (int i = 0; i < 2; ++i)
        acc[r][i] += wv.x*xa[i].x + wv.y*xa[i].y + wv.z*xb[i].x + wv.w*xb[i].y;
    }
  }
}

__launch_bounds__(NT, 2)
__global__ void speller_main(const float* __restrict__ LF, const float* __restrict__ Emb,
                             const float* __restrict__ Wih, const float* __restrict__ Whh,
                             const float* __restrict__ bih, const float* __restrict__ bhh,
                             const float* __restrict__ Wp,  const float* __restrict__ bp,
                             const float* __restrict__ Wc,  const float* __restrict__ bc,
                             float* __restrict__ out, unsigned* __restrict__ wsu,
                             float* __restrict__ wsf) {
  const int blk = blockIdx.x, tid = threadIdx.x;
  unsigned myGen = 0;
  __shared__ LdsU lds;
  __shared__ float scr[784];
  __shared__ int  sint[300];

  const int ab = blk >> 4, atc = blk & 15;         // attention chunk identity
  const int aw = tid >> 6, aln = tid & 63;         // head / t-row lane

  // ---- persistent LF slice: LF[ab, atc*64+aln, aw*128 .. +127] ----
  float4 lfr[32];
  {
    const float4* src = (const float4*)(LF +
        (((size_t)ab*Tv + atc*64 + aln)*512 + aw*128));
#pragma unroll
    for (int q = 0; q < 32; ++q) lfr[q] = src[q];
  }

  // ---------------- one-time LDS weight preload (plain cached loads) -------
  if (blk < 256) {
    const int u0 = blk * 2;
    for (int idx = tid; idx < 8*1536; idx += NT) {
      int r = idx / 1536, k = idx - r*1536;
      int g = r >> 1, uu = r & 1;
      int row = g*512 + u0 + uu;
      lds.a.Wg[r][k] = (k < 1024) ? Wih[(size_t)row*1024 + k]
                                  : Whh[(size_t)row*512 + (k-1024)];
    }
    if (tid < 8) {
      int g = tid >> 1, uu = tid & 1, row = g*512 + u0 + uu;
      lds.a.gb[tid] = bih[row] + bhh[row];
    }
  } else {
    const int blk2 = blk - 256, v0 = blk2*20, rp0 = blk2*2;
    if (v0 < Vv) {
      for (int idx = tid; idx < 20*512; idx += NT) {
        int vi = idx >> 9, k = idx & 511;
        lds.b.Wc[vi][k] = Wc[(size_t)(v0+vi)*512 + k];
      }
      if (tid < 20) lds.b.bcl[tid] = bc[v0+tid];
    }
    for (int idx = tid; idx < 2048; idx += NT) {
      int r = idx >> 10, k = idx & 1023;
      lds.b.Wp[r][k] = Wp[(size_t)(rp0+r)*1024 + k];
    }
    if (tid < 2) lds.b.bpl[tid] = bp[rp0+tid];
  }
  __syncthreads();

  float acc[8][2];                   // carried partial gates (A-part pipeline)
  float c_reg[2][2];                 // cell state, lives in registers all run
#pragma unroll
  for (int uu = 0; uu < 2; ++uu)
#pragma unroll
    for (int i = 0; i < 2; ++i) c_reg[uu][i] = 0.f;
  float lgv[20];                     // logits carried phase4 -> next phase1

  // ---- prologue: A-part (ctx0|h0) of step 0's gates ----
  if (blk < 256) {
    const int ks = tid & 15, b0 = (tid >> 4) * 2;
#pragma unroll
    for (int r = 0; r < 8; ++r)
#pragma unroll
      for (int i = 0; i < 2; ++i) acc[r][i] = 0.f;
    gate_accum_A(acc, wsf, lds.a.Wg, ks, b0, 0);
  }

#pragma unroll 1
  for (int s = 0; s < STEPS; ++s) {
    const int wbuf = (s + 1) & 1;

    // ===== W1: emb-part + LSTM finish (blk<256) | out-write (>=256) ========
    if (blk < 256) {
      const int u0 = blk * 2;
      const int ks = tid & 15, b0 = (tid >> 4) * 2;
#pragma unroll 2
      for (int q = 0; q < 8; ++q) {          // emb: k in [0,512)
        const int k4 = (q*16 + ks)*4;
        float2 xa[2], xb[2];
#pragma unroll
        for (int i = 0; i < 2; ++i) {
          const float* p = wsf + XH + (size_t)(b0+i)*1024 + k4;
          xa[i] = ld8(p); xb[i] = ld8(p + 2);
        }
#pragma unroll
        for (int r = 0; r < 8; ++r) {
          float4 wv = *(const float4*)(&lds.a.Wg[r][k4]);
#pragma unroll
          for (int i = 0; i < 2; ++i)
            acc[r][i] += wv.x*xa[i].x + wv.y*xa[i].y + wv.z*xb[i].x + wv.w*xb[i].y;
        }
      }
#pragma unroll
      for (int r = 0; r < 8; ++r)
#pragma unroll
        for (int i = 0; i < 2; ++i) {
          float v = acc[r][i];
          v += __shfl_xor(v, 8); v += __shfl_xor(v, 4);
          v += __shfl_xor(v, 2); v += __shfl_xor(v, 1);
          acc[r][i] = v + lds.a.gb[r];
        }
      // fused LSTM pointwise (rows: i=uu, f=2+uu, g=4+uu, o=6+uu)
      float hnew[2][2];
#pragma unroll
      for (int uu = 0; uu < 2; ++uu)
#pragma unroll
        for (int i = 0; i < 2; ++i) {
          float cn = sigm(acc[2+uu][i]) * c_reg[uu][i]
                   + sigm(acc[uu][i]) * tanhf(acc[4+uu][i]);
          c_reg[uu][i] = cn;
          hnew[uu][i] = sigm(acc[6+uu][i]) * tanhf(cn);
        }
      if (ks == 0) {
#pragma unroll
        for (int i = 0; i < 2; ++i)
          st8(wsf + HB + wbuf*16384 + (size_t)(b0+i)*512 + u0,
              make_float2(hnew[0][i], hnew[1][i]));
      }
    } else if (s > 0) {
      const int blk2 = blk - 256;
      if (blk2 < 250) {
        const int v0 = blk2 * 20, bb = tid >> 3, ks = tid & 7;
        if (ks == 0) {
          float2 ml = ld8(wsf + MLS + 2*bb);
          float sub = ml.x + ml.y;
#pragma unroll
          for (int vi = 0; vi < 20; ++vi)
            out[(size_t)(s-1)*160000 + (size_t)bb*5000 + v0 + vi] = lgv[vi] - sub;
        }
      }
    }
    gsync(wsu, blk, tid, myGen);

    // ============ W2: attention from register-resident LF ===================
    {
      float* hs = scr;  // [512] decoder state
      {
        float2 hv = ld8(wsf + HB + wbuf*16384 + (size_t)ab*512 + tid*2);
        hs[tid*2] = hv.x; hs[tid*2+1] = hv.y;
      }
      __syncthreads();
      float e = 0.f;
      {
        const float4* hp = (const float4*)(hs + aw*128);
#pragma unroll
        for (int q = 0; q < 32; ++q) {
          float4 f = lfr[q], hh = hp[q];
          e += f.x*hh.x + f.y*hh.y + f.z*hh.z + f.w*hh.w;
        }
      }
      float m = e;
#pragma unroll
      for (int off = 32; off; off >>= 1) m = fmaxf(m, __shfl_xor(m, off));
      float p = expf(e - m);
      float l = p;
#pragma unroll
      for (int off = 32; off; off >>= 1) l += __shfl_xor(l, off);
      if (aw == 3) st4(wsf + E3 + (size_t)ab*1024 + atc*64 + aln, e);
      float* pr = wsf + PART + (size_t)((ab*4 + aw)*16 + atc)*130;
#pragma unroll
      for (int ch = 0; ch < 2; ++ch) {             // fully unrolled: lfr idx static
        float c[64];
#pragma unroll
        for (int q = 0; q < 16; ++q) {
          float4 f = lfr[ch*16 + q];
          c[4*q+0] = p*f.x; c[4*q+1] = p*f.y; c[4*q+2] = p*f.z; c[4*q+3] = p*f.w;
        }
#pragma unroll
        for (int o = 32; o >= 1; o >>= 1) {
#pragma unroll
          for (int j = 0; j < 32; ++j) {
            if (j < o) {
              float keep = (aln & o) ? c[j + o] : c[j];
              float send = (aln & o) ? c[j] : c[j + o];
              c[j] = keep + __shfl_xor(send, o);
            }
          }
        }
        st4(pr + 2 + ch*64 + aln, c[0]);
      }
      if (aln == 0) st8(pr, make_float2(m, l));
      __syncthreads();   // drains vmcnt: all this block's partials are in L3
      if (tid == 0) {
        unsigned old = add_rlx(&wsu[ACNT + ab*16], 1u);
        sint[0] = (old == (unsigned)(s*16 + 15));
      }
      __syncthreads();
      if (sint[0]) {                       // last arriver merges the 16 chunks
        fence_acq();                       // see the other 15 blocks' partials
        const int w2 = tid >> 6, ln2 = tid & 63;
        const float* pb = wsf + PART + (size_t)(ab*4 + w2)*16*130;
        float M = -1e30f;
        float mv[16], lv[16];
#pragma unroll
        for (int i = 0; i < 16; ++i) { float2 t = ld8(pb + i*130); mv[i] = t.x; lv[i] = t.y; M = fmaxf(M, t.x); }
        float L = 0.f;
        float sc[16];
#pragma unroll
        for (int i = 0; i < 16; ++i) { sc[i] = expf(mv[i] - M); L += lv[i] * sc[i]; }
        float cc0 = 0.f, cc1 = 0.f;
#pragma unroll
        for (int i = 0; i < 16; ++i) {
          float2 cx = ld8(pb + i*130 + 2 + 2*ln2);
          cc0 += sc[i]*cx.x; cc1 += sc[i]*cx.y;
        }
        float invL = 1.f / L;
        st8(wsf + XH + (size_t)ab*1024 + 512 + w2*128 + 2*ln2,
            make_float2(cc0*invL, cc1*invL));
        if (ln2 == 0) { scr[768 + w2*2] = M; scr[769 + w2*2] = L; }
        __syncthreads();
        float M3 = scr[768 + 6], iL3 = 1.f / scr[768 + 7];
        for (int i = tid; i < 1024; i += NT)
          out[(size_t)10240000 + ((size_t)(s*32 + ab))*1024 + i] =
              expf(ld4(wsf + E3 + (size_t)ab*1024 + i) - M3) * iL3;
      }
    }
    gsync(wsu, blk, tid, myGen);

    // ===== W3: MLP (blk>=256) || next-step A-part gates (blk<256) ==========
    if (blk >= 256) {
      const int blk2 = blk - 256, rp0 = blk2*2;
      const int bb = tid & 31, ks = tid >> 5;        // 8 K-windows of 128
      const float* xr = (ks < 4) ? (wsf + HB + wbuf*16384 + (size_t)bb*512 + ks*128)
                                 : (wsf + XH + (size_t)bb*1024 + (ks-4)*128 + 512);
      const int kb = ks * 128;
      const float4* w0 = (const float4*)(&lds.b.Wp[0][kb]);
      const float4* w1 = (const float4*)(&lds.b.Wp[1][kb]);
      float a0 = 0.f, a1 = 0.f;
#pragma unroll 8
      for (int q = 0; q < 32; ++q) {
        float2 xva = ld8(xr + q*4), xvb = ld8(xr + q*4 + 2);
        float4 wv0 = w0[q], wv1 = w1[q];
        a0 += wv0.x*xva.x + wv0.y*xva.y + wv0.z*xvb.x + wv0.w*xvb.y;
        a1 += wv1.x*xva.x + wv1.y*xva.y + wv1.z*xvb.x + wv1.w*xvb.y;
      }
      scr[ks*32 + bb] = a0; scr[256 + ks*32 + bb] = a1;
      __syncthreads();
      if (tid < 64) {
        int r = tid >> 5, b2 = tid & 31;
        float ssum = 0.f;
#pragma unroll
        for (int j = 0; j < 8; ++j) ssum += scr[r*256 + j*32 + b2];
        ssum += lds.b.bpl[r];
        st4(wsf + HID + (size_t)b2*512 + rp0 + r, fmaxf(ssum, 0.f));
      }
      __syncthreads();
    } else if (s < 63) {
      // pipeline: A-part (ctx|h) of step s+1's gates, overlapped with P3
      const int ks = tid & 15, b0 = (tid >> 4) * 2;
#pragma unroll
      for (int r = 0; r < 8; ++r)
#pragma unroll
        for (int i = 0; i < 2; ++i) acc[r][i] = 0.f;
      gate_accum_A(acc, wsf, lds.a.Wg, ks, b0, wbuf);
    }
    gsync(wsu, blk, tid, myGen);

    // ============ W4: logits + softmax/argmax partials; parallel merge ======
    if (blk >= 256) {
      const int blk2 = blk - 256;
      if (blk2 < 250) {
        const int v0 = blk2 * 20;
        const int bb = tid >> 3, ks = tid & 7;       // interleaved K chunks
#pragma unroll
        for (int vi = 0; vi < 20; ++vi) lgv[vi] = 0.f;
        const float* hb = wsf + HID + (size_t)bb*512;
#pragma unroll 1
        for (int half = 0; half < 2; ++half) {       // two K-halves: xr[8] regs
          float4 xr[8];
#pragma unroll
          for (int q = 0; q < 8; ++q) {
            const float* p = hb + ((half*8 + q)*8 + ks)*4;
            float2 a = ld8(p), b2v = ld8(p + 2);
            xr[q] = make_float4(a.x, a.y, b2v.x, b2v.y);
          }
#pragma unroll
          for (int vi = 0; vi < 20; ++vi) {
            float a = 0.f;
#pragma unroll
            for (int q = 0; q < 8; ++q) {
              float4 wv = *(const float4*)(&lds.b.Wc[vi][((half*8 + q)*8 + ks)*4]);
              a += wv.x*xr[q].x + wv.y*xr[q].y + wv.z*xr[q].z + wv.w*xr[q].w;
            }
            lgv[vi] += a;
          }
        }
#pragma unroll
        for (int vi = 0; vi < 20; ++vi) {
          float a = lgv[vi];
          a += __shfl_xor(a, 1); a += __shfl_xor(a, 2); a += __shfl_xor(a, 4);
          lgv[vi] = a + lds.b.bcl[vi];
        }
        float mych = lgv[0]; int ami = 0;
#pragma unroll
        for (int vi = 1; vi < 20; ++vi)
          if (lgv[vi] > mych) { mych = lgv[vi]; ami = vi; }
        float sume = 0.f;
#pragma unroll
        for (int vi = 0; vi < 20; ++vi) sume += expf(lgv[vi] - mych);
        if (ks == 0) {
          st4(wsf + PM + bb*256 + blk2, mych);
          st4(wsf + PSUM + bb*256 + blk2, sume);
          st4i((int*)(wsf + PIDX) + bb*256 + blk2, v0 + ami);
        }
      }
      __syncthreads();   // drain: this block's partials are in L3
      if (tid == 0 && blk2 < 250) add_rlx(&wsu[LCNT], 1u);
      // ---- parallel merge: block 256+b2 owns batch b2 (32 concurrent) ----
      if (blk2 < 32) {
        const int b2 = blk2;
        if (tid == 0) {
          while (ld_rlx(&wsu[LCNT]) < (unsigned)((s + 1) * 250))
            __builtin_amdgcn_s_sleep(8);
        }
        __syncthreads();               // all 250 partials drained to L3
        fence_acq();                   // invalidate stale L1/L2 copies
        float mv = -1e30f, sv = 0.f; int iv = 0x7fffffff;
        if (tid < 250) {
          mv = ld4(wsf + PM + b2*256 + tid);
          sv = ld4(wsf + PSUM + b2*256 + tid);
          iv = ld4i((const int*)(wsf + PIDX) + b2*256 + tid);
        }
        scr[tid] = mv; sint[40 + tid] = iv;
        __syncthreads();
        for (int off = 128; off; off >>= 1) {
          if (tid < off) {
            float m2 = scr[tid + off]; int i2 = sint[40 + tid + off];
            if (m2 > scr[tid] || (m2 == scr[tid] && i2 < sint[40 + tid])) {
              scr[tid] = m2; sint[40 + tid] = i2;
            }
          }
          __syncthreads();
        }
        float M = scr[0]; int tok = sint[40];
        __syncthreads();
        scr[tid] = sv * expf(mv - M);
        __syncthreads();
        for (int off = 128; off; off >>= 1) {
          if (tid < off) scr[tid] += scr[tid + off];
          __syncthreads();
        }
        if (tid == 0) st8(wsf + MLS + 2*b2, make_float2(M, logf(scr[0])));
        for (int i = tid; i < 256; i += NT) {
          const float2* er = (const float2*)(Emb + (size_t)tok*512);
          st8(wsf + XH + (size_t)b2*1024 + 2*i, er[i]);
        }
      }
    }
    gsync(wsu, blk, tid, myGen);
  }

  // ---------------- epilogue: step 63's log-softmax from registers ----------
  if (blk >= 256) {
    const int blk2 = blk - 256;
    if (blk2 < 250) {
      const int v0 = blk2 * 20, bb = tid >> 3, ks = tid & 7;
      if (ks == 0) {
        float2 ml = ld8(wsf + MLS + 2*bb);
        float sub = ml.x + ml.y;
#pragma unroll
        for (int vi = 0; vi < 20; ++vi)
          out[(size_t)63*160000 + (size_t)bb*5000 + v0 + vi] = lgv[vi] - sub;
      }
    }
  }
}

extern "C" void kernel_launch(void* const* d_in, const int* in_sizes, int n_in,
                              void* d_out, int out_size, void* d_ws, size_t ws_size,
                              hipStream_t stream) {
  (void)in_sizes; (void)n_in; (void)out_size; (void)ws_size;
  const float* LF  = (const float*)d_in[0];
  const float* Emb = (const float*)d_in[1];
  const float* Wih = (const float*)d_in[2];
  const float* Whh = (const float*)d_in[3];
  const float* bih = (const float*)d_in[4];
  const float* bhh = (const float*)d_in[5];
  const float* Wp  = (const float*)d_in[6];
  const float* bp  = (const float*)d_in[7];
  const float* Wc  = (const float*)d_in[8];
  const float* bc  = (const float*)d_in[9];
  float* out = (float*)d_out;
  unsigned* wsu = (unsigned*)d_ws;
  float* wsf = (float*)d_ws + WSU;

  speller_init<<<32, NT, 0, stream>>>(LF, Emb, wsf, wsu);
  speller_main<<<NB, NT, 0, stream>>>(LF, Emb, Wih, Whh, bih, bhh, Wp, bp, Wc, bc,
                                      out, wsu, wsf);
}

// Round 9
// 5856.633 us; speedup vs baseline: 1.5338x; 1.5338x over previous
//
#include <hip/hip_runtime.h>
#include <math.h>
#include <stdint.h>

// ---------------------------------------------------------------------------
// Speller decoder, persistent kernel, 512 blocks x 256 threads.
// R12 = R8 protocol (verified 6665us; R11's inline-asm loads failed
// correctness twice -> abandoned) + W3 MLP fused into gate blocks.
// The MLP hid=relu(Wp.[h,ctx]+bp) reads the SAME [h|ctx] broadcast the gate
// blocks' A-part reads in the same W3 window. Now each gate block owns Wp
// rows 2blk,2blk+1 (LDS Wpg[2][1536], gate-space K layout: ctx@512, h@1024);
// every x-chunk loaded for the A-part also feeds 2 Wp-row FMAs; partials
// reduce over the 16 k-lanes like the gates; ks==0 writes HID rows 2blk,
// 2blk+1 for its 2 batches. Logits blocks idle in W3. This deletes the MLP's
// ~32 MB/step coherent-read stream (1/3 of the total broadcast volume).
// R8: phase-1 A-part (ctx|h) pipelined into the W3 window. R7/R6: LF
// register-resident (phase-2 attention zero LF traffic; keep/send
// reduce-scatter). R5: parallel per-batch phase-4 merge. R3: monotonic
// counter barriers, relaxed AGENT-scope atomics through L3, fused LSTM.
// ---------------------------------------------------------------------------

#define NB 512
#define NT 256

constexpr int Tv = 1024, Vv = 5000, STEPS = 64;

// ---- u32 counter region (all monotonic, zeroed by init kernel) ----
constexpr int MCNT = 0;               // master barrier counter
constexpr int GEN  = 16;              // barrier generation
constexpr int GCNT = 64;              // 32 group counters, stride 16
constexpr int GFLG = 1024;            // 32 group release flags, stride 32
constexpr int ACNT = 2048;            // 32 attn-merge counters, stride 16
constexpr int LCNT = 2560;            // single logits-arrival counter
constexpr int WSU  = 4096;

// ---- float region offsets (wsf = (float*)ws + WSU) ----
constexpr int XH   = 0;                    // [32][1024] = emb(512) | ctx(512)
constexpr int HB   = XH + 32*1024;         // [2][32][512] h double-buffer
constexpr int HID  = HB + 2*32*512;        // [32][512]
constexpr int PART = HID + 32*512;         // [32][4][16][130] attn partials
constexpr int E3   = PART + 32*4*16*130;   // [32][1024] head-3 energies
constexpr int PM   = E3 + 32*1024;         // [32][256] chunk max
constexpr int PSUM = PM + 32*256;          // [32][256] chunk sumexp
constexpr int PIDX = PSUM + 32*256;        // [32][256] chunk argmax (int)
constexpr int MLS  = PIDX + 32*256;        // [32][2] (max, lse)

__device__ __forceinline__ float sigm(float x) { return 1.f / (1.f + expf(-x)); }

// ---- coherent (L3, sc0 sc1) access helpers: relaxed agent atomics ----
__device__ __forceinline__ float ld4(const float* p) {
  return __hip_atomic_load(const_cast<float*>(p), __ATOMIC_RELAXED, __HIP_MEMORY_SCOPE_AGENT);
}
__device__ __forceinline__ float2 ld8(const float* p) {
  unsigned long long u = __hip_atomic_load(
      reinterpret_cast<unsigned long long*>(const_cast<float*>(p)),
      __ATOMIC_RELAXED, __HIP_MEMORY_SCOPE_AGENT);
  union { unsigned long long u; float2 f; } c; c.u = u; return c.f;
}
__device__ __forceinline__ int ld4i(const int* p) {
  return (int)__hip_atomic_load(reinterpret_cast<unsigned*>(const_cast<int*>(p)),
                                __ATOMIC_RELAXED, __HIP_MEMORY_SCOPE_AGENT);
}
__device__ __forceinline__ void st4(float* p, float v) {
  __hip_atomic_store(p, v, __ATOMIC_RELAXED, __HIP_MEMORY_SCOPE_AGENT);
}
__device__ __forceinline__ void st8(float* p, float2 v) {
  union { float2 f; unsigned long long u; } c; c.f = v;
  __hip_atomic_store(reinterpret_cast<unsigned long long*>(p), c.u,
                     __ATOMIC_RELAXED, __HIP_MEMORY_SCOPE_AGENT);
}
__device__ __forceinline__ void st4i(int* p, int v) {
  __hip_atomic_store(reinterpret_cast<unsigned*>(p), (unsigned)v,
                     __ATOMIC_RELAXED, __HIP_MEMORY_SCOPE_AGENT);
}
__device__ __forceinline__ unsigned ld_rlx(unsigned* p) {
  return __hip_atomic_load(p, __ATOMIC_RELAXED, __HIP_MEMORY_SCOPE_AGENT);
}
__device__ __forceinline__ void st_rlx(unsigned* p, unsigned v) {
  __hip_atomic_store(p, v, __ATOMIC_RELAXED, __HIP_MEMORY_SCOPE_AGENT);
}
__device__ __forceinline__ unsigned add_rlx(unsigned* p, unsigned v) {
  return __hip_atomic_fetch_add(p, v, __ATOMIC_RELAXED, __HIP_MEMORY_SCOPE_AGENT);
}

// Device barrier: NO cache ops. __syncthreads drains vmcnt (sc1 stores are
// then in L3 = globally visible); counters/flags are relaxed sc1 atomics.
__device__ __forceinline__ void gsync(unsigned* wsu, int blk, int tid, unsigned& myGen) {
  __syncthreads();
  if (tid == 0) {
    const unsigned target = ++myGen;
    const int grp = blk >> 4;
    unsigned o = add_rlx(&wsu[GCNT + grp*16], 1u);
    if (o == target*16u - 1u) {
      unsigned o2 = add_rlx(&wsu[MCNT], 1u);
      if (o2 == target*32u - 1u) st_rlx(&wsu[GEN], target);
    }
    if ((blk & 15) == 0) {
      while (ld_rlx(&wsu[GEN]) != target) __builtin_amdgcn_s_sleep(8);
      st_rlx(&wsu[GFLG + grp*32], target);
    } else {
      while (ld_rlx(&wsu[GFLG + grp*32]) != target) __builtin_amdgcn_s_sleep(8);
    }
  }
  __syncthreads();
}

__global__ void speller_init(const float* __restrict__ LF, const float* __restrict__ Emb,
                             float* __restrict__ wsf, unsigned* __restrict__ wsu) {
  int b = blockIdx.x;
  for (int i = threadIdx.x; i < 512; i += NT) {
    st4(wsf + XH + b*1024 + i,       Emb[i]);                    // emb row 0
    st4(wsf + XH + b*1024 + 512 + i, LF[(size_t)b*Tv*512 + i]);  // ctx0 = LF[b,0,:]
    st4(wsf + HB + b*512 + i,        0.f);                       // h0 (buffer 0)
  }
  if (b == 0) for (int i = threadIdx.x; i < WSU; i += NT) st_rlx(wsu + i, 0u);
}

// Gate blocks: Wg = 8 gate rows; Wpg = 2 Wp rows in GATE-space K layout
// (k in [512,1024) = ctx -> Wp col k; k in [1024,1536) = h -> Wp col k-1024).
struct LdsA { float Wg[8][1536]; float Wpg[2][1536]; float gb[8]; float bpg[2]; };
struct LdsB { float Wc[20][512]; float bcl[20]; };
union  LdsU { LdsA a; LdsB b; };

// Fused A-part of next step's gates + this step's 2 MLP rows.
// K in [512,1536) = ctx | h; acc[8][2] gates, accW[2][2] Wp rows.
__device__ __forceinline__ void gate_accum_A(float acc[8][2], float accW[2][2],
                                             const float* __restrict__ wsf,
                                             const float (&Wg)[8][1536],
                                             const float (&Wpg)[2][1536],
                                             int ks, int b0, int hbuf) {
#pragma unroll 2
  for (int q = 0; q < 8; ++q) {              // ctx: k in [512,1024)
    const int k4 = 512 + (q*16 + ks)*4;
    float2 xa[2], xb[2];
#pragma unroll
    for (int i = 0; i < 2; ++i) {
      const float* p = wsf + XH + (size_t)(b0+i)*1024 + k4;
      xa[i] = ld8(p); xb[i] = ld8(p + 2);
    }
#pragma unroll
    for (int r = 0; r < 8; ++r) {
      float4 wv = *(const float4*)(&Wg[r][k4]);
#pragma unroll
      for (int i = 0; i < 2; ++i)
        acc[r][i] += wv.x*xa[i].x + wv.y*xa[i].y + wv.z*xb[i].x + wv.w*xb[i].y;
    }
#pragma unroll
    for (int r = 0; r < 2; ++r) {
      float4 wv = *(const float4*)(&Wpg[r][k4]);
#pragma unroll
      for (int i = 0; i < 2; ++i)
        accW[r][i] += wv.x*xa[i].x + wv.y*xa[i].y + wv.z*xb[i].x + wv.w*xb[i].y;
    }
  }
#pragma unroll 2
  for (int q = 0; q < 8; ++q) {              // h: k in [1024,1536)
    const int k4 = (q*16 + ks)*4;
    float2 xa[2], xb[2];
#pragma unroll
    for (int i = 0; i < 2; ++i) {
      const float* p = wsf + HB + hbuf*16384 + (size_t)(b0+i)*512 + k4;
      xa[i] = ld8(p); xb[i] = ld8(p + 2);
    }
#pragma unroll
    for (int r = 0; r < 8; ++r) {
      float4 wv = *(const float4*)(&Wg[r][1024 + k4]);
#pragma unroll
      for (int i = 0; i < 2; ++i)
        acc[r][i] += wv.x*xa[i].x + wv.y*xa[i].y + wv.z*xb[i].x + wv.w*xb[i].y;
    }
#pragma unroll
    for (int r = 0; r < 2; ++r) {
      float4 wv = *(const float4*)(&Wpg[r][1024 + k4]);
#pragma unroll
      for (int i = 0; i < 2; ++i)
        accW[r][i] += wv.x*xa[i].x + wv.y*xa[i].y + wv.z*xb[i].x + wv.w*xb[i].y;
    }
  }
}

__launch_bounds__(NT, 2)
__global__ void speller_main(const float* __restrict__ LF, const float* __restrict__ Emb,
                             const float* __restrict__ Wih, const float* __restrict__ Whh,
                             const float* __restrict__ bih, const float* __restrict__ bhh,
                             const float* __restrict__ Wp,  const float* __restrict__ bp,
                             const float* __restrict__ Wc,  const float* __restrict__ bc,
                             float* __restrict__ out, unsigned* __restrict__ wsu,
                             float* __restrict__ wsf) {
  const int blk = blockIdx.x, tid = threadIdx.x;
  unsigned myGen = 0;
  __shared__ LdsU lds;
  __shared__ float scr[784];
  __shared__ int  sint[300];

  const int ab = blk >> 4, atc = blk & 15;         // attention chunk identity
  const int aw = tid >> 6, aln = tid & 63;         // head / t-row lane

  // ---- persistent LF slice: LF[ab, atc*64+aln, aw*128 .. +127] ----
  float4 lfr[32];
  {
    const float4* src = (const float4*)(LF +
        (((size_t)ab*Tv + atc*64 + aln)*512 + aw*128));
#pragma unroll
    for (int q = 0; q < 32; ++q) lfr[q] = src[q];
  }

  // ---------------- one-time LDS weight preload (plain cached loads) -------
  if (blk < 256) {
    const int u0 = blk * 2;
    for (int idx = tid; idx < 8*1536; idx += NT) {
      int r = idx / 1536, k = idx - r*1536;
      int g = r >> 1, uu = r & 1;
      int row = g*512 + u0 + uu;
      lds.a.Wg[r][k] = (k < 1024) ? Wih[(size_t)row*1024 + k]
                                  : Whh[(size_t)row*512 + (k-1024)];
    }
    for (int idx = tid; idx < 2*1536; idx += NT) {
      int r = idx / 1536, k = idx - r*1536;
      float v = 0.f;
      if (k >= 512) v = (k < 1024) ? Wp[(size_t)(u0+r)*1024 + k]
                                   : Wp[(size_t)(u0+r)*1024 + (k-1024)];
      lds.a.Wpg[r][k] = v;
    }
    if (tid < 8) {
      int g = tid >> 1, uu = tid & 1, row = g*512 + u0 + uu;
      lds.a.gb[tid] = bih[row] + bhh[row];
    }
    if (tid < 2) lds.a.bpg[tid] = bp[u0 + tid];
  } else {
    const int blk2 = blk - 256, v0 = blk2*20;
    if (v0 < Vv) {
      for (int idx = tid; idx < 20*512; idx += NT) {
        int vi = idx >> 9, k = idx & 511;
        lds.b.Wc[vi][k] = Wc[(size_t)(v0+vi)*512 + k];
      }
      if (tid < 20) lds.b.bcl[tid] = bc[v0+tid];
    }
  }
  __syncthreads();

  float acc[8][2];                   // carried partial gates (A-part pipeline)
  float accW[2][2];                  // this-step MLP partials (W3-local)
  float c_reg[2][2];                 // cell state, lives in registers all run
#pragma unroll
  for (int uu = 0; uu < 2; ++uu)
#pragma unroll
    for (int i = 0; i < 2; ++i) c_reg[uu][i] = 0.f;
  float lgv[20];                     // logits carried phase4 -> next phase1

  // ---- prologue: A-part (ctx0|h0) of step 0's gates (accW discarded) ----
  if (blk < 256) {
    const int ks = tid & 15, b0 = (tid >> 4) * 2;
#pragma unroll
    for (int r = 0; r < 8; ++r)
#pragma unroll
      for (int i = 0; i < 2; ++i) acc[r][i] = 0.f;
#pragma unroll
    for (int r = 0; r < 2; ++r)
#pragma unroll
      for (int i = 0; i < 2; ++i) accW[r][i] = 0.f;
    gate_accum_A(acc, accW, wsf, lds.a.Wg, lds.a.Wpg, ks, b0, 0);
  }

#pragma unroll 1
  for (int s = 0; s < STEPS; ++s) {
    const int wbuf = (s + 1) & 1;

    // ===== W1: emb-part + LSTM finish (blk<256) | out-write (>=256) ========
    if (blk < 256) {
      const int u0 = blk * 2;
      const int ks = tid & 15, b0 = (tid >> 4) * 2;
#pragma unroll 2
      for (int q = 0; q < 8; ++q) {          // emb: k in [0,512)
        const int k4 = (q*16 + ks)*4;
        float2 xa[2], xb[2];
#pragma unroll
        for (int i = 0; i < 2; ++i) {
          const float* p = wsf + XH + (size_t)(b0+i)*1024 + k4;
          xa[i] = ld8(p); xb[i] = ld8(p + 2);
        }
#pragma unroll
        for (int r = 0; r < 8; ++r) {
          float4 wv = *(const float4*)(&lds.a.Wg[r][k4]);
#pragma unroll
          for (int i = 0; i < 2; ++i)
            acc[r][i] += wv.x*xa[i].x + wv.y*xa[i].y + wv.z*xb[i].x + wv.w*xb[i].y;
        }
      }
#pragma unroll
      for (int r = 0; r < 8; ++r)
#pragma unroll
        for (int i = 0; i < 2; ++i) {
          float v = acc[r][i];
          v += __shfl_xor(v, 8); v += __shfl_xor(v, 4);
          v += __shfl_xor(v, 2); v += __shfl_xor(v, 1);
          acc[r][i] = v + lds.a.gb[r];
        }
      // fused LSTM pointwise (rows: i=uu, f=2+uu, g=4+uu, o=6+uu)
      float hnew[2][2];
#pragma unroll
      for (int uu = 0; uu < 2; ++uu)
#pragma unroll
        for (int i = 0; i < 2; ++i) {
          float cn = sigm(acc[2+uu][i]) * c_reg[uu][i]
                   + sigm(acc[uu][i]) * tanhf(acc[4+uu][i]);
          c_reg[uu][i] = cn;
          hnew[uu][i] = sigm(acc[6+uu][i]) * tanhf(cn);
        }
      if (ks == 0) {
#pragma unroll
        for (int i = 0; i < 2; ++i)
          st8(wsf + HB + wbuf*16384 + (size_t)(b0+i)*512 + u0,
              make_float2(hnew[0][i], hnew[1][i]));
      }
    } else if (s > 0) {
      const int blk2 = blk - 256;
      if (blk2 < 250) {
        const int v0 = blk2 * 20, bb = tid >> 3, ks = tid & 7;
        if (ks == 0) {
          float2 ml = ld8(wsf + MLS + 2*bb);
          float sub = ml.x + ml.y;
#pragma unroll
          for (int vi = 0; vi < 20; ++vi)
            out[(size_t)(s-1)*160000 + (size_t)bb*5000 + v0 + vi] = lgv[vi] - sub;
        }
      }
    }
    gsync(wsu, blk, tid, myGen);

    // ============ W2: attention from register-resident LF ===================
    {
      float* hs = scr;  // [512] decoder state
      {
        float2 hv = ld8(wsf + HB + wbuf*16384 + (size_t)ab*512 + tid*2);
        hs[tid*2] = hv.x; hs[tid*2+1] = hv.y;
      }
      __syncthreads();
      float e = 0.f;
      {
        const float4* hp = (const float4*)(hs + aw*128);
#pragma unroll
        for (int q = 0; q < 32; ++q) {
          float4 f = lfr[q], hh = hp[q];
          e += f.x*hh.x + f.y*hh.y + f.z*hh.z + f.w*hh.w;
        }
      }
      float m = e;
#pragma unroll
      for (int off = 32; off; off >>= 1) m = fmaxf(m, __shfl_xor(m, off));
      float p = expf(e - m);
      float l = p;
#pragma unroll
      for (int off = 32; off; off >>= 1) l += __shfl_xor(l, off);
      if (aw == 3) st4(wsf + E3 + (size_t)ab*1024 + atc*64 + aln, e);
      float* pr = wsf + PART + (size_t)((ab*4 + aw)*16 + atc)*130;
#pragma unroll
      for (int ch = 0; ch < 2; ++ch) {             // fully unrolled: lfr idx static
        float c[64];
#pragma unroll
        for (int q = 0; q < 16; ++q) {
          float4 f = lfr[ch*16 + q];
          c[4*q+0] = p*f.x; c[4*q+1] = p*f.y; c[4*q+2] = p*f.z; c[4*q+3] = p*f.w;
        }
#pragma unroll
        for (int o = 32; o >= 1; o >>= 1) {
#pragma unroll
          for (int j = 0; j < 32; ++j) {
            if (j < o) {
              float keep = (aln & o) ? c[j + o] : c[j];
              float send = (aln & o) ? c[j] : c[j + o];
              c[j] = keep + __shfl_xor(send, o);
            }
          }
        }
        st4(pr + 2 + ch*64 + aln, c[0]);
      }
      if (aln == 0) st8(pr, make_float2(m, l));
      __syncthreads();   // drains vmcnt: all this block's partials are in L3
      if (tid == 0) {
        unsigned old = add_rlx(&wsu[ACNT + ab*16], 1u);
        sint[0] = (old == (unsigned)(s*16 + 15));
      }
      __syncthreads();
      if (sint[0]) {                       // last arriver merges the 16 chunks
        const int w2 = tid >> 6, ln2 = tid & 63;
        const float* pb = wsf + PART + (size_t)(ab*4 + w2)*16*130;
        float M = -1e30f;
        float mv[16], lv[16];
#pragma unroll
        for (int i = 0; i < 16; ++i) { float2 t = ld8(pb + i*130); mv[i] = t.x; lv[i] = t.y; M = fmaxf(M, t.x); }
        float L = 0.f;
        float sc[16];
#pragma unroll
        for (int i = 0; i < 16; ++i) { sc[i] = expf(mv[i] - M); L += lv[i] * sc[i]; }
        float cc0 = 0.f, cc1 = 0.f;
#pragma unroll
        for (int i = 0; i < 16; ++i) {
          float2 cx = ld8(pb + i*130 + 2 + 2*ln2);
          cc0 += sc[i]*cx.x; cc1 += sc[i]*cx.y;
        }
        float invL = 1.f / L;
        st8(wsf + XH + (size_t)ab*1024 + 512 + w2*128 + 2*ln2,
            make_float2(cc0*invL, cc1*invL));
        if (ln2 == 0) { scr[768 + w2*2] = M; scr[769 + w2*2] = L; }
        __syncthreads();
        float M3 = scr[768 + 6], iL3 = 1.f / scr[768 + 7];
        for (int i = tid; i < 1024; i += NT)
          out[(size_t)10240000 + ((size_t)(s*32 + ab))*1024 + i] =
              expf(ld4(wsf + E3 + (size_t)ab*1024 + i) - M3) * iL3;
      }
    }
    gsync(wsu, blk, tid, myGen);

    // ===== W3: gate blocks: fused next-step A-part gates + THIS step's MLP ==
    if (blk < 256) {
      const int ks = tid & 15, b0 = (tid >> 4) * 2;
#pragma unroll
      for (int r = 0; r < 8; ++r)
#pragma unroll
        for (int i = 0; i < 2; ++i) acc[r][i] = 0.f;
#pragma unroll
      for (int r = 0; r < 2; ++r)
#pragma unroll
        for (int i = 0; i < 2; ++i) accW[r][i] = 0.f;
      gate_accum_A(acc, accW, wsf, lds.a.Wg, lds.a.Wpg, ks, b0, wbuf);
      // reduce MLP partials over the 16 k-lanes; ReLU; write HID rows 2blk+-
#pragma unroll
      for (int r = 0; r < 2; ++r)
#pragma unroll
        for (int i = 0; i < 2; ++i) {
          float v = accW[r][i];
          v += __shfl_xor(v, 8); v += __shfl_xor(v, 4);
          v += __shfl_xor(v, 2); v += __shfl_xor(v, 1);
          accW[r][i] = v + lds.a.bpg[r];
        }
      if (ks == 0) {
#pragma unroll
        for (int i = 0; i < 2; ++i)
          st8(wsf + HID + (size_t)(b0+i)*512 + blk*2,
              make_float2(fmaxf(accW[0][i], 0.f), fmaxf(accW[1][i], 0.f)));
      }
    }
    gsync(wsu, blk, tid, myGen);

    // ============ W4: logits + softmax/argmax partials; parallel merge ======
    if (blk >= 256) {
      const int blk2 = blk - 256;
      if (blk2 < 250) {
        const int v0 = blk2 * 20;
        const int bb = tid >> 3, ks = tid & 7;       // interleaved K chunks
#pragma unroll
        for (int vi = 0; vi < 20; ++vi) lgv[vi] = 0.f;
        const float* hb = wsf + HID + (size_t)bb*512;
#pragma unroll 1
        for (int half = 0; half < 2; ++half) {       // two K-halves: xr[8] regs
          float4 xr[8];
#pragma unroll
          for (int q = 0; q < 8; ++q) {
            const float* p = hb + ((half*8 + q)*8 + ks)*4;
            float2 a = ld8(p), b2v = ld8(p + 2);
            xr[q] = make_float4(a.x, a.y, b2v.x, b2v.y);
          }
#pragma unroll
          for (int vi = 0; vi < 20; ++vi) {
            float a = 0.f;
#pragma unroll
            for (int q = 0; q < 8; ++q) {
              float4 wv = *(const float4*)(&lds.b.Wc[vi][((half*8 + q)*8 + ks)*4]);
              a += wv.x*xr[q].x + wv.y*xr[q].y + wv.z*xr[q].z + wv.w*xr[q].w;
            }
            lgv[vi] += a;
          }
        }
#pragma unroll
        for (int vi = 0; vi < 20; ++vi) {
          float a = lgv[vi];
          a += __shfl_xor(a, 1); a += __shfl_xor(a, 2); a += __shfl_xor(a, 4);
          lgv[vi] = a + lds.b.bcl[vi];
        }
        float mych = lgv[0]; int ami = 0;
#pragma unroll
        for (int vi = 1; vi < 20; ++vi)
          if (lgv[vi] > mych) { mych = lgv[vi]; ami = vi; }
        float sume = 0.f;
#pragma unroll
        for (int vi = 0; vi < 20; ++vi) sume += expf(lgv[vi] - mych);
        if (ks == 0) {
          st4(wsf + PM + bb*256 + blk2, mych);
          st4(wsf + PSUM + bb*256 + blk2, sume);
          st4i((int*)(wsf + PIDX) + bb*256 + blk2, v0 + ami);
        }
      }
      __syncthreads();   // drain: this block's partials are in L3
      if (tid == 0 && blk2 < 250) add_rlx(&wsu[LCNT], 1u);
      // ---- parallel merge: block 256+b2 owns batch b2 (32 concurrent) ----
      if (blk2 < 32) {
        const int b2 = blk2;
        if (tid == 0) {
          while (ld_rlx(&wsu[LCNT]) < (unsigned)((s + 1) * 250))
            __builtin_amdgcn_s_sleep(8);
        }
        __syncthreads();               // all 250 partials visible
        float mv = -1e30f, sv = 0.f; int iv = 0x7fffffff;
        if (tid < 250) {
          mv = ld4(wsf + PM + b2*256 + tid);
          sv = ld4(wsf + PSUM + b2*256 + tid);
          iv = ld4i((const int*)(wsf + PIDX) + b2*256 + tid);
        }
        scr[tid] = mv; sint[40 + tid] = iv;
        __syncthreads();
        for (int off = 128; off; off >>= 1) {
          if (tid < off) {
            float m2 = scr[tid + off]; int i2 = sint[40 + tid + off];
            if (m2 > scr[tid] || (m2 == scr[tid] && i2 < sint[40 + tid])) {
              scr[tid] = m2; sint[40 + tid] = i2;
            }
          }
          __syncthreads();
        }
        float M = scr[0]; int tok = sint[40];
        __syncthreads();
        scr[tid] = sv * expf(mv - M);
        __syncthreads();
        for (int off = 128; off; off >>= 1) {
          if (tid < off) scr[tid] += scr[tid + off];
          __syncthreads();
        }
        if (tid == 0) st8(wsf + MLS + 2*b2, make_float2(M, logf(scr[0])));
        for (int i = tid; i < 256; i += NT) {
          const float2* er = (const float2*)(Emb + (size_t)tok*512);
          st8(wsf + XH + (size_t)b2*1024 + 2*i, er[i]);
        }
      }
    }
    gsync(wsu, blk, tid, myGen);
  }

  // ---------------- epilogue: step 63's log-softmax from registers ----------
  if (blk >= 256) {
    const int blk2 = blk - 256;
    if (blk2 < 250) {
      const int v0 = blk2 * 20, bb = tid >> 3, ks = tid & 7;
      if (ks == 0) {
        float2 ml = ld8(wsf + MLS + 2*bb);
        float sub = ml.x + ml.y;
#pragma unroll
        for (int vi = 0; vi < 20; ++vi)
          out[(size_t)63*160000 + (size_t)bb*5000 + v0 + vi] = lgv[vi] - sub;
      }
    }
  }
}

extern "C" void kernel_launch(void* const* d_in, const int* in_sizes, int n_in,
                              void* d_out, int out_size, void* d_ws, size_t ws_size,
                              hipStream_t stream) {
  (void)in_sizes; (void)n_in; (void)out_size; (void)ws_size;
  const float* LF  = (const float*)d_in[0];
  const float* Emb = (const float*)d_in[1];
  const float* Wih = (const float*)d_in[2];
  const float* Whh = (const float*)d_in[3];
  const float* bih = (const float*)d_in[4];
  const float* bhh = (const float*)d_in[5];
  const float* Wp  = (const float*)d_in[6];
  const float* bp  = (const float*)d_in[7];
  const float* Wc  = (const float*)d_in[8];
  const float* bc  = (const float*)d_in[9];
  float* out = (float*)d_out;
  unsigned* wsu = (unsigned*)d_ws;
  float* wsf = (float*)d_ws + WSU;

  speller_init<<<32, NT, 0, stream>>>(LF, Emb, wsf, wsu);
  speller_main<<<NB, NT, 0, stream>>>(LF, Emb, Wih, Whh, bih, bhh, Wp, bp, Wc, bc,
                                      out, wsu, wsf);
}